// Round 11
// baseline (18.851 us; speedup 1.0000x reference)
//
#include <hip/hip_runtime.h>
#include <math.h>

// Reranker tie-aware RankNet loss — R11 (R10 + occupancy A/B: 1 row/wave).
// B=4096 rows, n=64. 256 blocks x 1024 thr; 16 waves/block, 1 row/wave
// (4 waves/SIMD, 1 block/CU). Tail protocol identical to R10 (nb=256).
//
// Pair coverage: for d=1..32, lane a handles unordered pair {a, b=(a+d)&63}
// (d=32 restricted to lanes<32). Direction from own group bounds [s,e]:
//   m1 = b>e -> ordered (a,b) masked-in;  m2 = b<s -> ordered (b,a) masked-in
// Shared factor (1 + 2^-|t|), t=pb-pa; relu part = [m1|m2]*max(t,0) - [m2]*t.
// ONE v_exp_f32 per unordered pair; one v_log_f32 per lane (log-of-product,
// 8 chains x <=8 factors in (1,2] -> no overflow). cnt analytic = 63-e.
//
// Finalize (R9/R10-validated, contention-free): per block one relaxed u64
// store of packed {cnt,sum}; 2-level arrival (32 groups of 8 on private
// 128-B lines -> root, 32 RMWs); counters never reset (mod-8/mod-32 winner,
// poison-proof); store -> vmcnt(0) -> RMW ordering; winner block reduces all
// partials in FIXED order -> bit-deterministic.

#define N 64
#define WAVES 16                // waves per 1024-thread block
#define LN2 0.6931471805599453f
#define LOG2E 1.4426950408889634f

__global__ __launch_bounds__(1024) void rank_loss_fused(
    const float* __restrict__ logits, const int* __restrict__ kd,
    float* __restrict__ out,
    unsigned long long* __restrict__ partials,  // [nb] packed {cnt,sum}
    unsigned* __restrict__ gcnt,                // 32 counters, stride 32 u32
    unsigned* __restrict__ root,                // 1 counter
    int B, int nb)
{
    const int lane = threadIdx.x & 63;
    const int wave = threadIdx.x >> 6;

    __shared__ float ssum[WAVES], scnt[WAVES];
    __shared__ int finalizeFlag;
    if (threadIdx.x == 0) finalizeFlag = 0;

    // 8 product chains; 4+4 relu accumulator chains
    float p0=1.f,p1=1.f,p2=1.f,p3=1.f,p4=1.f,p5=1.f,p6=1.f,p7=1.f;
    float rm0=0.f,rm1=0.f,rm2=0.f,rm3=0.f;     // sum of [m1|m2]*max(t,0)
    float rt0=0.f,rt1=0.f,rt2=0.f,rt3=0.f;     // sum of [m2]*t
    float cnt = 0.f;

    const int row = blockIdx.x * WAVES + wave;  // exactly B rows, no guard math
    if (row < B) {
        const int base = row * N + lane;
        const int   k   = kd[base];
        const float pa  = logits[base] * LOG2E;

        const int kprev = __shfl_up(k, 1);
        const int knext = __shfl_down(k, 1);
        const unsigned long long endm   = __ballot(lane == 63 || k != knext);
        const unsigned long long startm = __ballot(lane == 0  || k != kprev);
        const int e = lane + __builtin_ctzll(endm >> lane);          // bit63 set
        const int s = lane - __builtin_clzll(startm << (63 - lane)); // bit0 set
        cnt = (float)(63 - e);

        #pragma unroll 32
        for (int d = 1; d <= 32; ++d) {
            const int b  = (lane + d) & 63;
            const float pb = __shfl(pa, b);
            const float t  = pb - pa;
            const float g  = __builtin_amdgcn_exp2f(-fabsf(t));
            const bool live = (d < 32) | (lane < 32);   // folds for d<32
            const bool m1 = (b > e) & live;
            const bool m2 = (b < s) & live;
            const bool mne = m1 | m2;
            const float gm = mne ? g : 0.0f;
            const float mx = mne ? fmaxf(t, 0.0f) : 0.0f;
            const float tm = m2 ? t : 0.0f;
            switch (d & 7) {   // literal when unrolled
                case 0: p0 = fmaf(gm, p0, p0); break;
                case 1: p1 = fmaf(gm, p1, p1); break;
                case 2: p2 = fmaf(gm, p2, p2); break;
                case 3: p3 = fmaf(gm, p3, p3); break;
                case 4: p4 = fmaf(gm, p4, p4); break;
                case 5: p5 = fmaf(gm, p5, p5); break;
                case 6: p6 = fmaf(gm, p6, p6); break;
                default: p7 = fmaf(gm, p7, p7); break;
            }
            switch (d & 3) {
                case 0: rm0 += mx; rt0 += tm; break;
                case 1: rm1 += mx; rt1 += tm; break;
                case 2: rm2 += mx; rt2 += tm; break;
                default: rm3 += mx; rt3 += tm; break;
            }
        }
    }

    float prod = ((p0 * p1) * (p2 * p3)) * ((p4 * p5) * (p6 * p7));
    float rsum = ((rm0 + rm1) + (rm2 + rm3)) - ((rt0 + rt1) + (rt2 + rt3));
    float psum = rsum + __builtin_amdgcn_logf(prod);   // v_log_f32 == log2

    #pragma unroll
    for (int off = 32; off; off >>= 1) {
        psum += __shfl_down(psum, off);
        cnt  += __shfl_down(cnt,  off);
    }
    if (lane == 0) { ssum[wave] = psum; scnt[wave] = cnt; }
    __syncthreads();

    if (threadIdx.x == 0) {
        float sv = 0.f, cv = 0.f;
        #pragma unroll
        for (int w = 0; w < WAVES; ++w) { sv += ssum[w]; cv += scnt[w]; }

        unsigned long long pv =
            ((unsigned long long)__float_as_uint(cv) << 32) |
            (unsigned long long)__float_as_uint(sv);
        __hip_atomic_store(&partials[blockIdx.x], pv,
                           __ATOMIC_RELAXED, __HIP_MEMORY_SCOPE_AGENT);
        asm volatile("s_waitcnt vmcnt(0)" ::: "memory");

        const unsigned g = (unsigned)blockIdx.x >> 3;     // 32 groups of 8
        unsigned go = __hip_atomic_fetch_add(&gcnt[g * 32], 1u,
                           __ATOMIC_RELAXED, __HIP_MEMORY_SCOPE_AGENT);
        if ((go & 7u) == 7u) {
            asm volatile("s_waitcnt vmcnt(0)" ::: "memory");
            unsigned ro = __hip_atomic_fetch_add(root, 1u,
                               __ATOMIC_RELAXED, __HIP_MEMORY_SCOPE_AGENT);
            if ((ro & 31u) == 31u) {                      // 32 winners/replay
                asm volatile("s_waitcnt vmcnt(0)" ::: "memory");
                finalizeFlag = 1;
            }
        }
    }
    __syncthreads();

    if (finalizeFlag) {          // exactly one block per replay; fixed order
        const int t = threadIdx.x;
        float sv = 0.f, cv = 0.f;
        if (t < 256) {                          // nb = 256, one partial/thread
            unsigned long long pv = __hip_atomic_load(&partials[t],
                               __ATOMIC_RELAXED, __HIP_MEMORY_SCOPE_AGENT);
            sv = __uint_as_float((unsigned)(pv & 0xffffffffull));
            cv = __uint_as_float((unsigned)(pv >> 32));
        }
        #pragma unroll
        for (int off = 32; off; off >>= 1) {
            sv += __shfl_down(sv, off);
            cv += __shfl_down(cv, off);
        }
        __shared__ float fs[WAVES], fc[WAVES];
        if (lane == 0) { fs[wave] = sv; fc[wave] = cv; }
        __syncthreads();
        if (t == 0) {
            float S = 0.f, C = 0.f;
            #pragma unroll
            for (int w = 0; w < 4; ++w) { S += fs[w]; C += fc[w]; }  // waves 4..15 hold 0-init? no:
            // waves 4..15 of the finalizer block wrote fs/fc too (zero or data);
            // only waves 0..3 hold the 256 partials (t<256). Sum those only.
            out[0] = S * LN2 / C;
        }
    }
}

extern "C" void kernel_launch(void* const* d_in, const int* in_sizes, int n_in,
                              void* d_out, int out_size, void* d_ws, size_t ws_size,
                              hipStream_t stream) {
    const float* logits = (const float*)d_in[0];
    const int*   kd     = (const int*)d_in[1];
    float*       out    = (float*)d_out;
    const int B  = in_sizes[1] / N;                  // 4096
    const int nb = B / WAVES;                        // 256 blocks

    unsigned long long* partials = (unsigned long long*)d_ws;          // 2 KiB
    unsigned* gcnt = (unsigned*)((char*)d_ws + 8192);   // 32 x 128 B lines
    unsigned* root = (unsigned*)((char*)d_ws + 16384);  // own line

    rank_loss_fused<<<nb, WAVES * 64, 0, stream>>>(logits, kd, out, partials,
                                                   gcnt, root, B, nb);
}

// Round 12
// 12.957 us; speedup vs baseline: 1.4549x; 1.4549x over previous
//
#include <hip/hip_runtime.h>
#include <math.h>

// Reranker tie-aware RankNet loss — R12 (= R10 config + d-space masks).
// B=4096 rows, n=64. 256 blocks x 512 thr; 8 waves/block, 2 rows/wave.
//
// Pair coverage: for d=1..32, lane a handles unordered pair {a, b=(a+d)&63}
// (d=32 restricted to lanes<32). Direction masks in d-space with per-row
// thresholds E=e-lane, L=64-lane, S=s-lane+64  (s,e = own group bounds):
//   no-wrap (d<L):  m1 = d>E   (b>e);   m2 impossible (b>=lane>=s)
//   wrap   (d>=L):  m1 impossible (b<lane<=e);  m2 = d<S   (b<s)
// Both directions share factor (1 + 2^-|t|), t=pb-pa;
// relu part = [m1|m2]*max(t,0) - [m2]*t   (max(-t,0)=max(t,0)-t).
// ONE v_exp_f32 per unordered pair; one v_log_f32 per lane (log-of-product,
// 8 chains x <=8 factors in (1,2] -> no overflow). cnt analytic = 63-e.
//
// Finalize (R9/R10-validated, contention-free): per block one relaxed u64
// store of packed {cnt,sum}; 2-level arrival counters (32 groups of 8 on
// private 128-B lines -> root, 32 RMWs); counters never reset (mod-8/mod-32
// winner detection is poison-proof); store -> vmcnt(0) -> RMW ordering; the
// winner block loads all partials and reduces in FIXED order.

#define N 64
#define WAVES 8                 // waves per 512-thread block
#define RPW 2                   // rows per wave
#define LN2 0.6931471805599453f
#define LOG2E 1.4426950408889634f

__global__ __launch_bounds__(512) void rank_loss_fused(
    const float* __restrict__ logits, const int* __restrict__ kd,
    float* __restrict__ out,
    unsigned long long* __restrict__ partials,  // [nb] packed {cnt,sum}
    unsigned* __restrict__ gcnt,                // 32 counters, stride 32 u32
    unsigned* __restrict__ root,                // 1 counter
    int B, int nb)
{
    const int lane = threadIdx.x & 63;
    const int wave = threadIdx.x >> 6;

    __shared__ float ssum[WAVES], scnt[WAVES];
    __shared__ int finalizeFlag;
    if (threadIdx.x == 0) finalizeFlag = 0;

    // 8 product chains; 4+4 relu accumulator chains
    float p0=1.f,p1=1.f,p2=1.f,p3=1.f,p4=1.f,p5=1.f,p6=1.f,p7=1.f;
    float rm0=0.f,rm1=0.f,rm2=0.f,rm3=0.f;     // sum of [m1|m2]*max(t,0)
    float rt0=0.f,rt1=0.f,rt2=0.f,rt3=0.f;     // sum of [m2]*t
    float cnt = 0.f;

    #pragma unroll
    for (int rr = 0; rr < RPW; ++rr) {
        const int row = (blockIdx.x * WAVES + wave) * RPW + rr;
        if (row < B) {
            const int base = row * N + lane;
            const int   k   = kd[base];
            const float pa  = logits[base] * LOG2E;

            const int kprev = __shfl_up(k, 1);
            const int knext = __shfl_down(k, 1);
            const unsigned long long endm   = __ballot(lane == 63 || k != knext);
            const unsigned long long startm = __ballot(lane == 0  || k != kprev);
            const int e = lane + __builtin_ctzll(endm >> lane);          // bit63 set
            const int s = lane - __builtin_clzll(startm << (63 - lane)); // bit0 set
            cnt += (float)(63 - e);

            const int E = e - lane;        // m1 threshold (no-wrap)
            const int L = 64 - lane;       // wrap boundary
            const int S = s + L;           // m2 threshold (wrap)

            #pragma unroll 32
            for (int d = 1; d <= 32; ++d) {
                const float pb = __shfl(pa, (lane + d) & 63);
                const float t  = pb - pa;
                const float g  = __builtin_amdgcn_exp2f(-fabsf(t));
                const bool nw = d < L;                  // literal-d compares
                bool m1 = (d > E) & nw;
                bool m2 = (!nw) & (d < S);
                if (d == 32) {                          // kill mirror dup
                    m1 = m1 & (lane < 32);
                    m2 = m2 & (lane < 32);
                }
                const bool mne = m1 | m2;
                const float gm = mne ? g : 0.0f;
                const float mx = mne ? fmaxf(t, 0.0f) : 0.0f;
                const float tm = m2 ? t : 0.0f;
                switch (d & 7) {   // literal when unrolled
                    case 0: p0 = fmaf(gm, p0, p0); break;
                    case 1: p1 = fmaf(gm, p1, p1); break;
                    case 2: p2 = fmaf(gm, p2, p2); break;
                    case 3: p3 = fmaf(gm, p3, p3); break;
                    case 4: p4 = fmaf(gm, p4, p4); break;
                    case 5: p5 = fmaf(gm, p5, p5); break;
                    case 6: p6 = fmaf(gm, p6, p6); break;
                    default: p7 = fmaf(gm, p7, p7); break;
                }
                switch (d & 3) {
                    case 0: rm0 += mx; rt0 += tm; break;
                    case 1: rm1 += mx; rt1 += tm; break;
                    case 2: rm2 += mx; rt2 += tm; break;
                    default: rm3 += mx; rt3 += tm; break;
                }
            }
        }
    }

    float prod = ((p0 * p1) * (p2 * p3)) * ((p4 * p5) * (p6 * p7));
    float rsum = ((rm0 + rm1) + (rm2 + rm3)) - ((rt0 + rt1) + (rt2 + rt3));
    float psum = rsum + __builtin_amdgcn_logf(prod);   // v_log_f32 == log2

    #pragma unroll
    for (int off = 32; off; off >>= 1) {
        psum += __shfl_down(psum, off);
        cnt  += __shfl_down(cnt,  off);
    }
    if (lane == 0) { ssum[wave] = psum; scnt[wave] = cnt; }
    __syncthreads();

    if (threadIdx.x == 0) {
        float sv = 0.f, cv = 0.f;
        #pragma unroll
        for (int w = 0; w < WAVES; ++w) { sv += ssum[w]; cv += scnt[w]; }

        unsigned long long pv =
            ((unsigned long long)__float_as_uint(cv) << 32) |
            (unsigned long long)__float_as_uint(sv);
        __hip_atomic_store(&partials[blockIdx.x], pv,
                           __ATOMIC_RELAXED, __HIP_MEMORY_SCOPE_AGENT);
        asm volatile("s_waitcnt vmcnt(0)" ::: "memory");

        const unsigned g = (unsigned)blockIdx.x >> 3;     // 32 groups of 8
        unsigned go = __hip_atomic_fetch_add(&gcnt[g * 32], 1u,
                           __ATOMIC_RELAXED, __HIP_MEMORY_SCOPE_AGENT);
        if ((go & 7u) == 7u) {
            asm volatile("s_waitcnt vmcnt(0)" ::: "memory");
            unsigned ro = __hip_atomic_fetch_add(root, 1u,
                               __ATOMIC_RELAXED, __HIP_MEMORY_SCOPE_AGENT);
            if ((ro & 31u) == 31u) {                      // 32 winners/replay
                asm volatile("s_waitcnt vmcnt(0)" ::: "memory");
                finalizeFlag = 1;
            }
        }
    }
    __syncthreads();

    if (finalizeFlag) {          // exactly one block per replay; fixed order
        const int t = threadIdx.x;
        float sv = 0.f, cv = 0.f;
        if (t < 256) {                          // nb = 256, one partial/thread
            unsigned long long pv = __hip_atomic_load(&partials[t],
                               __ATOMIC_RELAXED, __HIP_MEMORY_SCOPE_AGENT);
            sv = __uint_as_float((unsigned)(pv & 0xffffffffull));
            cv = __uint_as_float((unsigned)(pv >> 32));
        }
        #pragma unroll
        for (int off = 32; off; off >>= 1) {
            sv += __shfl_down(sv, off);
            cv += __shfl_down(cv, off);
        }
        __shared__ float fs[WAVES], fc[WAVES];
        if (lane == 0) { fs[wave] = sv; fc[wave] = cv; }
        __syncthreads();
        if (t == 0) {
            float S = 0.f, C = 0.f;
            #pragma unroll
            for (int w = 0; w < 4; ++w) { S += fs[w]; C += fc[w]; }  // partials live in waves 0..3
            out[0] = S * LN2 / C;
        }
    }
}

extern "C" void kernel_launch(void* const* d_in, const int* in_sizes, int n_in,
                              void* d_out, int out_size, void* d_ws, size_t ws_size,
                              hipStream_t stream) {
    const float* logits = (const float*)d_in[0];
    const int*   kd     = (const int*)d_in[1];
    float*       out    = (float*)d_out;
    const int B  = in_sizes[1] / N;                  // 4096
    const int nb = B / (WAVES * RPW);                // 256 blocks

    unsigned long long* partials = (unsigned long long*)d_ws;          // 2 KiB
    unsigned* gcnt = (unsigned*)((char*)d_ws + 8192);   // 32 x 128 B lines
    unsigned* root = (unsigned*)((char*)d_ws + 16384);  // own line

    rank_loss_fused<<<nb, WAVES * 64, 0, stream>>>(logits, kd, out, partials,
                                                   gcnt, root, B, nb);
}

// Round 13
// 12.008 us; speedup vs baseline: 1.5698x; 1.0790x over previous
//
#include <hip/hip_runtime.h>
#include <math.h>

// Reranker tie-aware RankNet loss — R13 (revert to R10, the measured optimum).
// B=4096 rows, n=64. 256 blocks x 512 thr; 8 waves/block, 2 rows/wave.
//
// Pair coverage: for d=1..32, lane a handles unordered pair {a, b=(a+d)&63}
// (d=32 restricted to lanes<32 — its mirror would duplicate). Each unordered
// pair appears exactly once. Direction from OWN lane's group bounds [s,e]
// (start index s, end index e; start array is non-decreasing):
//   m1 = b>e  -> start(a)<start(b): ordered pair (a,b), term softplus(pb-pa)
//   m2 = b<s  -> start(b)<start(a): ordered pair (b,a), term softplus(pa-pb)
// Both directions share factor (1 + 2^-|t|), t = pb-pa, and
//   max(-t,0) = max(t,0) - t  =>  relu part = [m1|m2]*max(t,0) - [m2]*t.
// => ONE v_exp_f32 per unordered pair (32 slots vs 64), one v_log per lane.
// Product chains: 64 factors/lane over 8 chains -> <= 2^8 each, no overflow.
// cnt analytic: sum over rows of (63 - e)  (== ref mask count).
//
// Finalize (R9-validated, contention-free): per block one relaxed u64 store
// of packed {cnt,sum}; 2-level arrival counters (32 groups of 8 on private
// 128-B lines -> root, 32 RMWs); counters never reset (mod-8/mod-32 winner
// detection is poison-proof); store -> vmcnt(0) -> RMW ordering chain; the
// winner block loads all partials and reduces in FIXED order.

#define N 64
#define WAVES 8                 // waves per 512-thread block
#define RPW 2                   // rows per wave
#define LN2 0.6931471805599453f
#define LOG2E 1.4426950408889634f

__global__ __launch_bounds__(512) void rank_loss_fused(
    const float* __restrict__ logits, const int* __restrict__ kd,
    float* __restrict__ out,
    unsigned long long* __restrict__ partials,  // [nb] packed {cnt,sum}
    unsigned* __restrict__ gcnt,                // 32 counters, stride 32 u32
    unsigned* __restrict__ root,                // 1 counter
    int B, int nb)
{
    const int lane = threadIdx.x & 63;
    const int wave = threadIdx.x >> 6;

    __shared__ float ssum[WAVES], scnt[WAVES];
    __shared__ int finalizeFlag;
    if (threadIdx.x == 0) finalizeFlag = 0;

    // 8 product chains; 4+4 relu accumulator chains
    float p0=1.f,p1=1.f,p2=1.f,p3=1.f,p4=1.f,p5=1.f,p6=1.f,p7=1.f;
    float rm0=0.f,rm1=0.f,rm2=0.f,rm3=0.f;     // sum of [m1|m2]*max(t,0)
    float rt0=0.f,rt1=0.f,rt2=0.f,rt3=0.f;     // sum of [m2]*t
    float cnt = 0.f;

    #pragma unroll
    for (int rr = 0; rr < RPW; ++rr) {
        const int row = (blockIdx.x * WAVES + wave) * RPW + rr;
        if (row < B) {
            const int base = row * N + lane;
            const int   k   = kd[base];
            const float pa  = logits[base] * LOG2E;

            const int kprev = __shfl_up(k, 1);
            const int knext = __shfl_down(k, 1);
            const unsigned long long endm   = __ballot(lane == 63 || k != knext);
            const unsigned long long startm = __ballot(lane == 0  || k != kprev);
            const int e = lane + __builtin_ctzll(endm >> lane);        // bit63 set
            const int s = lane - __builtin_clzll(startm << (63 - lane)); // bit0 set
            cnt += (float)(63 - e);

            #pragma unroll 32
            for (int d = 1; d <= 32; ++d) {
                const int b  = (lane + d) & 63;
                const float pb = __shfl(pa, b);
                const float t  = pb - pa;
                const float g  = __builtin_amdgcn_exp2f(-fabsf(t));
                const bool live = (d < 32) | (lane < 32);   // d folds when unrolled
                const bool m1 = (b > e) & live;
                const bool m2 = (b < s) & live;
                const bool mne = m1 | m2;
                const float gm = mne ? g : 0.0f;
                const float mx = mne ? fmaxf(t, 0.0f) : 0.0f;
                const float tm = m2 ? t : 0.0f;
                switch (d & 7) {   // literal when unrolled
                    case 0: p0 = fmaf(gm, p0, p0); break;
                    case 1: p1 = fmaf(gm, p1, p1); break;
                    case 2: p2 = fmaf(gm, p2, p2); break;
                    case 3: p3 = fmaf(gm, p3, p3); break;
                    case 4: p4 = fmaf(gm, p4, p4); break;
                    case 5: p5 = fmaf(gm, p5, p5); break;
                    case 6: p6 = fmaf(gm, p6, p6); break;
                    default: p7 = fmaf(gm, p7, p7); break;
                }
                switch (d & 3) {
                    case 0: rm0 += mx; rt0 += tm; break;
                    case 1: rm1 += mx; rt1 += tm; break;
                    case 2: rm2 += mx; rt2 += tm; break;
                    default: rm3 += mx; rt3 += tm; break;
                }
            }
        }
    }

    float prod = ((p0 * p1) * (p2 * p3)) * ((p4 * p5) * (p6 * p7));
    float rsum = ((rm0 + rm1) + (rm2 + rm3)) - ((rt0 + rt1) + (rt2 + rt3));
    float psum = rsum + __builtin_amdgcn_logf(prod);   // v_log_f32 == log2

    #pragma unroll
    for (int off = 32; off; off >>= 1) {
        psum += __shfl_down(psum, off);
        cnt  += __shfl_down(cnt,  off);
    }
    if (lane == 0) { ssum[wave] = psum; scnt[wave] = cnt; }
    __syncthreads();

    if (threadIdx.x == 0) {
        float sv = 0.f, cv = 0.f;
        #pragma unroll
        for (int w = 0; w < WAVES; ++w) { sv += ssum[w]; cv += scnt[w]; }

        unsigned long long pv =
            ((unsigned long long)__float_as_uint(cv) << 32) |
            (unsigned long long)__float_as_uint(sv);
        __hip_atomic_store(&partials[blockIdx.x], pv,
                           __ATOMIC_RELAXED, __HIP_MEMORY_SCOPE_AGENT);
        asm volatile("s_waitcnt vmcnt(0)" ::: "memory");

        const unsigned g = (unsigned)blockIdx.x >> 3;     // 32 groups of 8
        unsigned go = __hip_atomic_fetch_add(&gcnt[g * 32], 1u,
                           __ATOMIC_RELAXED, __HIP_MEMORY_SCOPE_AGENT);
        if ((go & 7u) == 7u) {
            asm volatile("s_waitcnt vmcnt(0)" ::: "memory");
            unsigned ro = __hip_atomic_fetch_add(root, 1u,
                               __ATOMIC_RELAXED, __HIP_MEMORY_SCOPE_AGENT);
            if ((ro & 31u) == 31u) {                      // 32 winners/replay
                asm volatile("s_waitcnt vmcnt(0)" ::: "memory");
                finalizeFlag = 1;
            }
        }
    }
    __syncthreads();

    if (finalizeFlag) {          // exactly one block per replay; fixed order
        const int t = threadIdx.x;
        float sv = 0.f, cv = 0.f;
        if (t < 256) {                          // nb = 256, one partial/thread
            unsigned long long pv = __hip_atomic_load(&partials[t],
                               __ATOMIC_RELAXED, __HIP_MEMORY_SCOPE_AGENT);
            sv = __uint_as_float((unsigned)(pv & 0xffffffffull));
            cv = __uint_as_float((unsigned)(pv >> 32));
        }
        #pragma unroll
        for (int off = 32; off; off >>= 1) {
            sv += __shfl_down(sv, off);
            cv += __shfl_down(cv, off);
        }
        __shared__ float fs[WAVES], fc[WAVES];
        if (lane == 0) { fs[wave] = sv; fc[wave] = cv; }
        __syncthreads();
        if (t == 0) {
            float S = 0.f, C = 0.f;
            #pragma unroll
            for (int w = 0; w < 4; ++w) { S += fs[w]; C += fc[w]; }  // partials live in waves 0..3
            out[0] = S * LN2 / C;
        }
    }
}

extern "C" void kernel_launch(void* const* d_in, const int* in_sizes, int n_in,
                              void* d_out, int out_size, void* d_ws, size_t ws_size,
                              hipStream_t stream) {
    const float* logits = (const float*)d_in[0];
    const int*   kd     = (const int*)d_in[1];
    float*       out    = (float*)d_out;
    const int B  = in_sizes[1] / N;                  // 4096
    const int nb = B / (WAVES * RPW);                // 256 blocks

    unsigned long long* partials = (unsigned long long*)d_ws;          // 2 KiB
    unsigned* gcnt = (unsigned*)((char*)d_ws + 8192);   // 32 x 128 B lines
    unsigned* root = (unsigned*)((char*)d_ws + 16384);  // own line

    rank_loss_fused<<<nb, WAVES * 64, 0, stream>>>(logits, kd, out, partials,
                                                   gcnt, root, B, nb);
}